// Round 10
// baseline (83.997 us; speedup 1.0000x reference)
//
#include <hip/hip_runtime.h>
#include <hip/hip_cooperative_groups.h>
#include <math.h>

namespace cg = cooperative_groups;

// CTC batch cost. Single cooperative kernel (256 blocks x 256 threads):
//  Phase A (all blocks): random-gather log2(y_pred[b,t,cls]+eps) -> ws,
//     full-chip spread, 7 independent gathers per thread (MLP).
//  grid.sync()
//  Phase B (blocks 0..63): stage [T][49] slice into LDS, wave-0 register DP
//     with DPP wave_shr:1, raw v_exp_f32/v_log_f32 in the chain.
// Removes one kernel launch + inter-kernel drain vs the 2-kernel pipeline.
// Falls back to the two-kernel path if ws is too small (shouldn't happen).

#define NEGV (-1e30f)
#define EPSV (1e-7f)

constexpr int B = 64, T = 128, C = 4000, L = 48;
constexpr int BLANK = C - 1;       // 3999
constexpr int NCLS = L + 1;        // 49: slots 0..47 = labels, 48 = blank
constexpr int TOTAL = B * T * NCLS;  // 401408

#if __has_builtin(__builtin_amdgcn_exp2f)
__device__ __forceinline__ float fexp2(float x) { return __builtin_amdgcn_exp2f(x); }
#else
__device__ __forceinline__ float fexp2(float x) { return exp2f(x); }
#endif
#if __has_builtin(__builtin_amdgcn_logf)
__device__ __forceinline__ float flog2(float x) { return __builtin_amdgcn_logf(x); }
#else
__device__ __forceinline__ float flog2(float x) { return log2f(x); }
#endif

// lane shift up by 1 via DPP wave_shr:1 (VALU latency). Lane 0 gets NEGV.
__device__ __forceinline__ float dpp_shr1_neg(float x) {
    int r = __builtin_amdgcn_update_dpp(__float_as_int(NEGV), __float_as_int(x),
                                        0x138 /*wave_shr:1*/, 0xF, 0xF, false);
    return __int_as_float(r);
}

// DP body (shared by coop phase B and fallback K2), b = batch row.
__device__ __forceinline__ void dp_body(
    int b, int tid,
    const int* __restrict__ y_true,
    const int* __restrict__ label_len,
    const float* __restrict__ lp_ws,
    float* __restrict__ out,
    float* lp_s /* [T*NCLS+32] LDS */, int* lab_s /* [L] LDS */, int* ll_sp)
{
    if (tid < L) {
        int ll = label_len[b];
        if (tid == 0) *ll_sp = ll;
        int v = y_true[b * L + tid];
        lab_s[tid] = (tid < ll) ? v : BLANK;   // pad with blank as reference
    }

    // coalesced float4 stage: 6272 floats = 1568 float4
    const float4* src = (const float4*)(lp_ws + (size_t)b * T * NCLS);
    float4* dst = (float4*)lp_s;
    for (int i = tid; i < (T * NCLS) / 4; i += 256) dst[i] = src[i];
    __syncthreads();

    if (tid >= 64) return;              // DP on wave 0 only
    const int lane = tid;
    const int ll = *ll_sp;

    const int myLab   = (lane < L) ? lab_s[lane] : BLANK;
    const int prevLab = (lane >= 1 && lane - 1 < L) ? lab_s[lane - 1] : BLANK;
    const bool allow2 = (lane >= 1) && (myLab != BLANK) && (myLab != prevLab);

    float a0 = (lane == 0) ? lp_s[48] : NEGV;   // t=0, state 0 (blank)
    float a1 = (lane == 0) ? lp_s[0]  : NEGV;   // t=0, state 1 (label 0)

    // prefetch lp for t=1
    float lpb_n = lp_s[1 * NCLS + 48];
    float lpl_n = (lane < L) ? lp_s[1 * NCLS + lane] : 0.0f;

    for (int t = 1; t < T; ++t) {
        float lpb = lpb_n, lpl = lpl_n;
        int tn = (t + 1 < T) ? t + 1 : t;
        lpb_n = lp_s[tn * NCLS + 48];
        lpl_n = (lane < L) ? lp_s[tn * NCLS + lane] : 0.0f;

        float pa1 = dpp_shr1_neg(a1);   // alpha[2l-1] from lane l-1

        // state 2l: lse2(a0, pa1) + lpb
        float m0 = fmaxf(a0, pa1);
        float n0 = fminf(a0, pa1);
        float r0 = (m0 + lpb) + flog2(1.0f + fexp2(n0 - m0));

        // state 2l+1: lse3(a1, a0, allow2 ? pa1 : NEG) + lpl
        float c12 = allow2 ? pa1 : NEGV;
        float m1 = fmaxf(fmaxf(a1, a0), c12);
        float r1 = (m1 + lpl) + flog2(fexp2(a1 - m1) + fexp2(a0 - m1) +
                                      fexp2(c12 - m1));

        a0 = r0;
        a1 = (lane < L) ? r1 : NEGV;    // states beyond S stay dead
    }

    float ab = __shfl(a0, ll);          // alpha[2*ll]
    float al = __shfl(a1, ll - 1);      // alpha[2*ll-1]
    if (lane == 0) {
        float m = fmaxf(ab, al);
        float ll2 = m + flog2(fexp2(ab - m) + fexp2(al - m));
        out[b] = -ll2 * 0.69314718055994531f;   // back to natural log
    }
}

// ---------------- Cooperative fused kernel ----------------
__global__ __launch_bounds__(256) void ctc_coop(
    const int* __restrict__ y_true,     // [B, L]
    const float* __restrict__ y_pred,   // [B, T, C]
    const int* __restrict__ label_len,  // [B, 1]
    float* __restrict__ lp_ws,          // [B, T, NCLS]
    float* __restrict__ out)            // [B, 1]
{
    const int tid = threadIdx.x;
    const int blk = blockIdx.x;

    __shared__ float lp_s[T * NCLS + 32];
    __shared__ int   lab_s[L];
    __shared__ int   ll_s;

    // ---- Phase A: gather (all 256 blocks, 7 independent gathers/thread) ----
    const int gbase = blk * 256 + tid;
    #pragma unroll
    for (int k = 0; k < 7; ++k) {
        int idx = gbase + k * 65536;
        if (idx < TOTAL) {
            int bt = idx / NCLS;
            int j  = idx - bt * NCLS;
            int b  = bt >> 7;           // / T
            int cls = BLANK;
            if (j < L) {
                int ll = label_len[b];
                cls = (j < ll) ? y_true[b * L + j] : BLANK;
            }
            float p = y_pred[(size_t)bt * C + cls];
            lp_ws[idx] = flog2(p + EPSV);
        }
    }

    __threadfence();                    // device-scope: cross-XCD visibility
    cg::this_grid().sync();

    // ---- Phase B: DP on blocks 0..63 ----
    if (blk >= B) return;
    dp_body(blk, tid, y_true, label_len, lp_ws, out, lp_s, lab_s, &ll_s);
}

// ---------------- Fallback: two-kernel path (small ws) ----------------
__global__ __launch_bounds__(256) void gather_kernel(
    const int* __restrict__ y_true,
    const float* __restrict__ y_pred,
    const int* __restrict__ label_len,
    float* __restrict__ lp_ws)
{
    int idx = blockIdx.x * 256 + threadIdx.x;
    if (idx >= TOTAL) return;
    int bt = idx / NCLS;
    int j  = idx - bt * NCLS;
    int b  = bt >> 7;
    int cls = BLANK;
    if (j < L) {
        int ll = label_len[b];
        cls = (j < ll) ? y_true[b * L + j] : BLANK;
    }
    float p = y_pred[(size_t)bt * C + cls];
    lp_ws[idx] = flog2(p + EPSV);
}

__global__ __launch_bounds__(256) void dp_kernel(
    const int* __restrict__ y_true,
    const int* __restrict__ label_len,
    const float* __restrict__ lp_ws,
    float* __restrict__ out)
{
    __shared__ float lp_s[T * NCLS + 32];
    __shared__ int   lab_s[L];
    __shared__ int   ll_s;
    dp_body(blockIdx.x, threadIdx.x, y_true, label_len, lp_ws, out,
            lp_s, lab_s, &ll_s);
}

extern "C" void kernel_launch(void* const* d_in, const int* in_sizes, int n_in,
                              void* d_out, int out_size, void* d_ws, size_t ws_size,
                              hipStream_t stream) {
    const int*   y_true       = (const int*)d_in[0];
    const float* y_pred       = (const float*)d_in[1];
    const int*   label_length = (const int*)d_in[2];
    float*       out          = (float*)d_out;

    const size_t need = (size_t)TOTAL * sizeof(float);
    if (ws_size >= need) {
        float* lp_ws = (float*)d_ws;
        void* args[] = { (void*)&y_true, (void*)&y_pred, (void*)&label_length,
                         (void*)&lp_ws, (void*)&out };
        hipLaunchCooperativeKernel(reinterpret_cast<void*>(ctc_coop),
                                   dim3(256), dim3(256), args, 0, stream);
    } else {
        // tiny-ws fallback: two-kernel pipeline needs ws too; if even that
        // fails, there is no valid path — but harness provides ample ws.
        float* lp_ws = (float*)d_ws;
        gather_kernel<<<(TOTAL + 255) / 256, 256, 0, stream>>>(
            y_true, y_pred, label_length, lp_ws);
        dp_kernel<<<B, 256, 0, stream>>>(y_true, label_length, lp_ws, out);
    }
}